// Round 13
// baseline (9875.390 us; speedup 1.0000x reference)
//
#include <hip/hip_runtime.h>

typedef unsigned short u16;
typedef __attribute__((ext_vector_type(8))) short short8;   // 8 x bf16
typedef __attribute__((ext_vector_type(4))) float float4v;  // MFMA acc

#define NT 1024  // threads per worker WG: 16 waves = 4/SIMD (max TLP at 1 WG/CU)

// ---- output offsets (floats) ----
#define O_MEANS 0
#define O_LS    1310720
#define O_RHO   2621440
#define O_PI    3276800
#define O_EOS   3932160
#define O_H0H   3964928
#define O_H0C   3990528
#define O_H1H   4016128
#define O_H1C   4041728
#define O_H2H   4067328
#define O_H2C   4092928
#define O_PW    4118528
#define O_PK    4122368
#define O_AL    4123008

// bar layout (u32): [x*32] x=0..7 claim counters per XCD;
// group g region at 256+g*1024: arrival flags [i*32] i=0..24, flushed-gen [832].
#define GBASE(g)  (256 + (g)*1024)
#define FGOFF     832
#define SPIN_MAX  (1L<<19)

struct P {
  const float *strokes; const int *text; const int *tlen;
  const float *h0h,*h0c,*h1h,*h1c,*h2h,*h2c,*pw,*pk;
  const float *bih0,*bhh0,*bih1,*bhh1,*bih2,*bhh2;
  const float *Wwin,*bwin;
  const float *bmu,*bls,*brho,*bpi,*beos;
  u16 *B0,*B1,*B2,*Bw0,*BP;     // fragment-packed weights
  u16 *A0,*A1,*A2;              // fragment-packed activations per step
  u16 *y0,*y1,*y2;              // bf16 row-major hidden histories [T][64][400]
  float *obuf;                  // 3 rounds x 5 banks x [30][64] o-partials (atomic-only)
  unsigned *bar;                // claims + per-group flags + flushed gens
  float *out;
};

__device__ __forceinline__ u16 f2bf(float f){
  unsigned int x = __float_as_uint(f);
  unsigned int r = x + 0x7FFFu + ((x >> 16) & 1u);
  return (u16)(r >> 16);
}
// A-pack element (t, batch b, k) for a layer with KB k-blocks.
// block = (t*4 + b/16)*KB + k/32 ; inside: lane=((k>>3)&3)*16+(b&15), elem k&7
__device__ __forceinline__ size_t aidx(int t, int b, int k, int KB){
  return ((size_t)((t*4 + (b>>4))*KB + (k>>5)))*512
       + (size_t)(((((k>>3)&3)*16) + (b&15))*8 + (k&7));
}
__device__ __forceinline__ float sigm(float x){ return 1.f/(1.f+__expf(-x)); }
__device__ __forceinline__ float tanh_f(float x){ return 2.f/(1.f+__expf(-2.f*x)) - 1.f; }

// ---------------- weight packing ----------------
__global__ void kpackB(const float* __restrict__ Wih, const float* __restrict__ Whh,
                       u16* __restrict__ dst, int KB, int kx, int stride, int total){
  int tid = blockIdx.x*256 + threadIdx.x;
  if (tid >= total) return;
  int e = tid & 511, blk = tid >> 9;
  int kb = blk % KB, tile = (blk / KB) & 3, s = blk / (KB*4);
  int lane = e >> 3, j = e & 7;
  int q = lane >> 4, n = lane & 15;
  int k = kb*32 + q*8 + j;
  int col = s*16 + tile*4 + (n&3);
  int g = (n>>2)*400 + col;
  float v = 0.f;
  if (k < kx) v = Wih[(size_t)g*stride + k];
  else if (k < kx + 400) v = Whh[(size_t)g*400 + (k - kx)];
  dst[tid] = f2bf(v);
}

// inline-w weights for L0: [25][4][2][512], from Wih0 cols 3..62
__global__ void kpackBw(const float* __restrict__ Wih0, u16* __restrict__ dst){
  int tid = blockIdx.x*256 + threadIdx.x;
  if (tid >= 25*4*2*512) return;
  int e = tid & 511, blk = tid >> 9;
  int kb = blk & 1, tile = (blk>>1) & 3, s = blk >> 3;
  int lane = e >> 3, j = e & 7;
  int q = lane >> 4, n = lane & 15;
  int k = kb*32 + q*8 + j;
  int col = s*16 + tile*4 + (n&3);
  int g = (n>>2)*400 + col;
  dst[tid] = (k < 60) ? f2bf(Wih0[(size_t)g*63 + 3 + k]) : (u16)0;
}

// projection weights: cols 0..39 mu, 40..79 ls, 80..99 rho, 100..119 pi, 120 eos
__global__ void kpackBP(const float* __restrict__ Wmu, const float* __restrict__ Wls,
                        const float* __restrict__ Wrho, const float* __restrict__ Wpi,
                        const float* __restrict__ Weos, u16* __restrict__ dst){
  int tid = blockIdx.x*256 + threadIdx.x;
  if (tid >= 8*38*512) return;
  int e = tid & 511, blk = tid >> 9;
  int lane = e >> 3, j = e & 7;
  int ns = blk / 38, kb = blk % 38;
  int q = lane >> 4, n = lane & 15;
  int k = kb*32 + q*8 + j;
  int col = ns*16 + n;
  float v = 0.f;
  if (k < 1200){
    if (col < 40)       v = Wmu[(size_t)col*1200 + k];
    else if (col < 80)  v = Wls[(size_t)(col-40)*1200 + k];
    else if (col < 100) v = Wrho[(size_t)(col-80)*1200 + k];
    else if (col < 120) v = Wpi[(size_t)(col-100)*1200 + k];
    else if (col == 120) v = Weos[k];
  }
  dst[tid] = f2bf(v);
}

// strokes rows + zero pads for all t (ws is 0xAA-poisoned every run)
__global__ void kfillA(P p){
  int tid = blockIdx.x*256 + threadIdx.x;
  if (tid >= 512*64*32) return;
  int it = tid & 31; int rr = tid >> 5; int b = rr & 63; int t = rr >> 6;
  const float* sx = p.strokes + ((size_t)t*64 + b)*3;
  if (it < 3)        p.A0[aidx(t,b,it,13)] = f2bf(sx[it]);
  else if (it < 16)  p.A0[aidx(t,b,400+it,13)] = 0;          // pads 403..415
  else if (it < 19)  p.A1[aidx(t,b,460+(it-16),27)] = f2bf(sx[it-16]);
  else if (it == 19) p.A1[aidx(t,b,863,27)] = 0;
  else if (it < 23)  p.A2[aidx(t,b,460+(it-20),27)] = f2bf(sx[it-20]);
  else if (it == 23) p.A2[aidx(t,b,863,27)] = 0;
}

// initial states + obuf/claims/flags zero
__global__ void kinit(P p){
  int tid = blockIdx.x*256 + threadIdx.x;
  if (tid < 25600){ int b=tid/400, j=tid%400; p.A0[aidx(0,b,3+j,13)] = f2bf(p.h0h[tid]); }
  else if (tid < 51200){ int i=tid-25600; int b=i/400, j=i%400; p.A1[aidx(0,b,463+j,27)] = f2bf(p.h1h[i]); }
  else if (tid < 76800){ int i=tid-51200; int b=i/400, j=i%400; p.A2[aidx(0,b,463+j,27)] = f2bf(p.h2h[i]); }
  else if (tid < 105600){ p.obuf[tid-76800] = 0.f; }
  else if (tid < 109696){ p.bar[tid-105600] = 0u; }
}

// ---------------- intra-XCD 25-WG barrier, fence-free, 1-hop (R11-proven) ----------------
__device__ __forceinline__ void gsyncx(unsigned* fl, int s, unsigned target){
  __threadfence_block();   // drain this wave's stores into the shared L2
  __syncthreads();         // all waves drained
  if (threadIdx.x == 0)
    __hip_atomic_store(&fl[s*32], target, __ATOMIC_RELAXED, __HIP_MEMORY_SCOPE_AGENT);
  if (threadIdx.x < 25){
    long c = 0;
    while (__hip_atomic_load(&fl[threadIdx.x*32], __ATOMIC_RELAXED, __HIP_MEMORY_SCOPE_AGENT) < target){
      __builtin_amdgcn_s_sleep(1);
      if (++c > SPIN_MAX) break;   // failsafe: wrong answer, never a hang
    }
  }
  __syncthreads();
}

// wait for a producer group's FLUSHED generation (pre-satisfied by pipeline lag)
__device__ __forceinline__ void waitgen(const unsigned* gw, unsigned target){
  if (threadIdx.x == 0){
    long c = 0;
    while (__hip_atomic_load(gw, __ATOMIC_RELAXED, __HIP_MEMORY_SCOPE_AGENT) < target){
      __builtin_amdgcn_s_sleep(1);
      if (++c > SPIN_MAX) break;
    }
  }
  __syncthreads();
}

// ---------------- main persistent kernel: 3 XCD-local groups, 16 waves/WG ----------------
// 256 WGs (1 WG/CU by LDS => 32/XCD). Roles via XCC_ID claim. Wave w owns
// (b-quadrant bq = w&3, tile th = w>>2) -> exactly 1 column tile each.
__global__ __launch_bounds__(NT, 1) void kmain(P p){
  const int tid = threadIdx.x;
  const int lane = tid & 63, wave = tid >> 6;
  const int bq = wave & 3, th = wave >> 2;

  __shared__ int role2[2];
  if (tid == 0){
    unsigned x;
    asm volatile("s_getreg_b32 %0, hwreg(HW_REG_XCC_ID, 0, 4)" : "=s"(x));
    x &= 7u;
    unsigned sl = atomicAdd(&p.bar[x*32], 1u);
    role2[0] = (int)x; role2[1] = (int)sl;
  }
  __syncthreads();
  const int grp = role2[0];
  const int s   = role2[1];
  if (grp > 2 || s > 25) return;
  unsigned* fl = p.bar + GBASE(grp);

  if (s == 25){                       // flusher: wbl2 this XCD's L2 per round
    if (grp == 2) return;             // nobody consumes grp2's flush
    if (tid < 25){
      unsigned* fg = fl + FGOFF;
      for (unsigned rr = 1; rr <= 514; ++rr){
        long c = 0;
        while (__hip_atomic_load(&fl[tid*32], __ATOMIC_RELAXED, __HIP_MEMORY_SCOPE_AGENT) < rr){
          __builtin_amdgcn_s_sleep(2);
          if (++c > SPIN_MAX) break;
        }
        if (tid == 0){
          __builtin_amdgcn_fence(__ATOMIC_RELEASE, "agent");   // waitcnt + wbl2
          __hip_atomic_store(fg, rr, __ATOMIC_RELAXED, __HIP_MEMORY_SCOPE_AGENT);
        }
      }
    }
    return;
  }

  const int lag = (grp == 0) ? 0 : (grp + 1);   // 0,2,3

  __shared__ u16  wB[55296];         // 110592 B weight slice (+ grp0 overlay)
  __shared__ float ldsg[64][65];     // gate tile [b][4 tiles *16 cols]
  __shared__ float clds[16][64];     // persistent cell state [jj][b]
  __shared__ float bsum[64];         // bias sums [jj*4+gate], this slice

  // grp0 overlays in wB[30720..55295] (49152 B available, 46328 used)
  u16* wBw = wB + 26624;                                   // 8 KB inline-w weights
  char* exb = (char*)(wB + 30720);
  float (*hsh)[64]  = (float (*)[64])(exb);                //  4096 B  h0 stage
  float (*wacc)[64] = (float (*)[64])(exb + 4096);         // 15360 B  w accum
  u16   (*wbf)[80]  = (u16   (*)[80])(exb + 19456);        // 10240 B  w A-operand
  float (*klds)[10] = (float (*)[10])(exb + 29696);        //  2560 B  kappa
  float (*ash)[10]  = (float (*)[10])(exb + 32256);
  float (*bsh)[10]  = (float (*)[10])(exb + 34816);
  float (*ksh)[10]  = (float (*)[10])(exb + 37376);        // end 39936
  float (*wwin_l)[16] = (float (*)[16])(exb + 39936);      //  1920 B Wwin slice
  unsigned char* text_l = (unsigned char*)(exb + 41856);   //  4096 B text (u8)
  int*   tlen_l = (int*)(exb + 45952);                     //   256 B
  float* bwin_l = (float*)(exb + 46208);                   //   120 B, end 46328

  const u16 *Ap; u16 *yr;
  const float *bi, *bh, *cin; int ohh, occ;
  if (grp == 0){ Ap=p.A0; yr=p.y0; bi=p.bih0; bh=p.bhh0; cin=p.h0c; ohh=O_H0H; occ=O_H0C; }
  else if (grp == 1){ Ap=p.A1; yr=p.y1; bi=p.bih1; bh=p.bhh1; cin=p.h1c; ohh=O_H1H; occ=O_H1C; }
  else { Ap=p.A2; yr=p.y2; bi=p.bih2; bh=p.bhh2; cin=p.h2c; ohh=O_H2H; occ=O_H2C; }

  // ---- stage weight slice into LDS (once) ----
  {
    const u16* gsrc; int cnt;
    if (grp == 0){ gsrc = p.B0 + (size_t)s*26624; cnt = 26624; }
    else if (grp == 1){ gsrc = p.B1 + (size_t)s*55296; cnt = 55296; }
    else { gsrc = p.B2 + (size_t)s*55296; cnt = 55296; }
    for (int i = tid*8; i < cnt; i += NT*8)
      *reinterpret_cast<short8*>(&wB[i]) = *reinterpret_cast<const short8*>(gsrc + i);
    if (grp == 0){
      const u16* gw = p.Bw0 + (size_t)s*4096;
      if (tid*8 < 4096)
        *reinterpret_cast<short8*>(wBw + tid*8) = *reinterpret_cast<const short8*>(gw + tid*8);
    }
  }

  if (tid < 1024){
    int jj = tid >> 6, b = tid & 63;
    clds[jj][b] = cin[b*400 + s*16 + jj];
  }
  if (tid < 64){
    int jj = tid >> 2, gg = tid & 3;
    bsum[tid] = bi[gg*400 + s*16 + jj] + bh[gg*400 + s*16 + jj];
  }
  if (grp == 0){
    if (tid < 640) klds[tid/10][tid%10] = p.pk[tid];
    for (int cell = tid; cell < 64*80; cell += NT){
      int b = cell/80, k = cell%80;
      wbf[b][k] = (k < 60) ? f2bf(p.pw[b*60 + k]) : (u16)0;
    }
    if (tid < 480) wwin_l[tid>>4][tid&15] = p.Wwin[(tid>>4)*400 + s*16 + (tid&15)];
    for (int cell = tid; cell < 4096; cell += NT)
      text_l[cell] = (unsigned char)p.text[cell];
    if (tid < 64) tlen_l[tid] = p.tlen[tid];
    if (tid < 30) bwin_l[tid] = p.bwin[tid];
  }
  __syncthreads();

  for (int r = 0; r < 515; ++r){
    const int t = r - lag;

    // ---- cross-group ordering via FLUSHED gens (pre-satisfied by lag) ----
    if (grp == 1 && r >= 2 && r <= 513) waitgen(p.bar + GBASE(0) + FGOFF, (unsigned)r);
    if (grp == 2 && r >= 3 && r <= 514) waitgen(p.bar + GBASE(1) + FGOFF, (unsigned)r);

    // ---- grp0: hoist obuf bank loads then A0 frags ----
    float ovs[2][5];
    if (grp == 0 && r >= 1 && r <= 512){
      const float* ob = p.obuf + (size_t)((r-1)%3)*9600;
      #pragma unroll
      for (int i = 0; i < 2; ++i){
        int cell = tid + i*NT;
        if (cell < 1920){
          #pragma unroll
          for (int bk = 0; bk < 5; ++bk)
            ovs[i][bk] = __hip_atomic_load(&ob[bk*1920 + cell], __ATOMIC_RELAXED, __HIP_MEMORY_SCOPE_AGENT);
        }
      }
    }
    short8 a0r[13];
    if (grp == 0 && t < 512){
      const u16* Ab = p.A0 + ((size_t)(t*4 + bq)*13)*512 + (size_t)lane*8;
      #pragma unroll
      for (int kb = 0; kb < 13; ++kb)
        a0r[kb] = *reinterpret_cast<const short8*>(Ab + (size_t)kb*512);
    }

    // ---- window finalize for t = r-1 (replicated across the 25 L0 WGs) ----
    if (grp == 0 && r >= 1 && r <= 512){
      const int tw = r - 1;
      #pragma unroll
      for (int i = 0; i < 2; ++i){
        int cell = tid + i*NT;
        if (cell < 1920){
          int b = cell & 63, n = cell >> 6;
          float o = ovs[i][0]+ovs[i][1]+ovs[i][2]+ovs[i][3]+ovs[i][4] + bwin_l[n];
          if (n < 10) ash[b][n] = __expf(o);
          else if (n < 20) bsh[b][n-10] = __expf(o);
          else { float kn = klds[b][n-20] + 0.05f*__expf(o); klds[b][n-20] = kn; ksh[b][n-20] = kn; }
        }
      }
      for (int cell = tid; cell < 3840; cell += NT) ((float*)wacc)[cell] = 0.f;
      __syncthreads();
      {
        // thread owns b = tid>>4, u = (tid&15)*4 .. +3 -> Gaussian params in regs
        const int b = tid >> 4, u0 = (tid & 15) * 4;
        const int tl = tlen_l[b];
        float ph[4] = {0.f, 0.f, 0.f, 0.f};
        if (u0 < tl){
          float av[10], bv[10], kv[10];
          #pragma unroll
          for (int n = 0; n < 10; ++n){ av[n]=ash[b][n]; bv[n]=bsh[b][n]; kv[n]=ksh[b][n]; }
          #pragma unroll
          for (int j = 0; j < 4; ++j){
            int u = u0 + j;
            if (u < tl){
              float phi = 0.f;
              #pragma unroll
              for (int n = 0; n < 10; ++n){
                float d = kv[n] - (float)u;
                phi += av[n]*__expf(-bv[n]*d*d);
              }
              ph[j] = phi;
              atomicAdd(&wacc[text_l[b*64 + u]][b], phi);
            }
          }
        }
        #pragma unroll
        for (int j = 0; j < 4; ++j){
          int cell = tid*4 + j;
          if (((cell*25) >> 12) == s)   // O_AL spread over 25 WGs
            p.out[O_AL + ((size_t)tw*64 + b)*64 + u0 + j] = ph[j];
        }
      }
      __syncthreads();
      for (int cell = tid; cell < 3840; cell += NT){
        int b = cell & 63, l = cell >> 6;
        u16 wv = f2bf(wacc[l][b]);
        wbf[b][l] = wv;
        if (s == 1) p.A1[aidx(tw,b,400+l,27)] = wv;
        if (s == 2) p.A2[aidx(tw,b,400+l,27)] = wv;
        if (s == 0 && tw == 511) p.out[O_PW + b*60 + l] = wacc[l][b];
      }
      if (s == 0 && tw == 511 && tid < 640) p.out[O_PK + tid] = klds[tid/10][tid%10];
      __syncthreads();
    }

    // ---- gate GEMM + LSTM pointwise ----
    if (t >= 0 && t < 512){
      float4v acc = {0.f,0.f,0.f,0.f};
      if (grp == 0){
        #pragma unroll
        for (int kb = 0; kb < 13; ++kb){
          short8 bf = *reinterpret_cast<const short8*>(wB + (size_t)(th*13 + kb)*512 + (size_t)lane*8);
          acc = __builtin_amdgcn_mfma_f32_16x16x32_bf16(a0r[kb], bf, acc, 0, 0, 0);
        }
        const int m = lane & 15, q = (lane >> 4) & 3;
        #pragma unroll
        for (int kb = 0; kb < 2; ++kb){
          short8 af = *reinterpret_cast<const short8*>(&wbf[bq*16 + m][kb*32 + q*8]);
          short8 bf = *reinterpret_cast<const short8*>(wBw + (size_t)((th*2 + kb))*512 + (size_t)lane*8);
          acc = __builtin_amdgcn_mfma_f32_16x16x32_bf16(af, bf, acc, 0, 0, 0);
        }
      } else {
        const u16* Ab = Ap + ((size_t)(t*4 + bq)*27)*512 + (size_t)lane*8;
        #pragma unroll
        for (int ch = 0; ch < 3; ++ch){      // 3x9 chunks: VGPR-safe at 4 waves/SIMD
          short8 a1r[9];
          #pragma unroll
          for (int kb = 0; kb < 9; ++kb)
            a1r[kb] = *reinterpret_cast<const short8*>(Ab + (size_t)(ch*9 + kb)*512);
          #pragma unroll
          for (int kb = 0; kb < 9; ++kb){
            short8 bf = *reinterpret_cast<const short8*>(wB + (size_t)(th*27 + ch*9 + kb)*512 + (size_t)lane*8);
            acc = __builtin_amdgcn_mfma_f32_16x16x32_bf16(a1r[kb], bf, acc, 0, 0, 0);
          }
        }
      }
      {
        const int c = lane & 15, rb = bq*16 + ((lane>>4)<<2);
        #pragma unroll
        for (int rr2 = 0; rr2 < 4; ++rr2)
          ldsg[rb+rr2][th*16 + c] = acc[rr2];
      }
      __syncthreads();
      if (tid < 1024){
        int jj = tid >> 6, b = tid & 63;
        int j = s*16 + jj, tt = jj >> 2, jo = jj & 3;
        float gi = ldsg[b][tt*16 +      jo] + bsum[jj*4 + 0];
        float gf = ldsg[b][tt*16 +  4 + jo] + bsum[jj*4 + 1];
        float gg = ldsg[b][tt*16 +  8 + jo] + bsum[jj*4 + 2];
        float go = ldsg[b][tt*16 + 12 + jo] + bsum[jj*4 + 3];
        float cp = clds[jj][b];
        float cn = sigm(gf)*cp + sigm(gi)*tanh_f(gg);
        float hh = sigm(go)*tanh_f(cn);
        clds[jj][b] = cn;
        u16 hb = f2bf(hh);
        yr[((size_t)t*64 + b)*400 + j] = hb;
        if (grp == 0){
          p.A1[aidx(t,b,j,27)] = hb;
          if (t < 511) p.A0[aidx(t+1,b,3+j,13)] = hb;
          hsh[jj][b] = hh;
        } else if (grp == 1){
          p.A2[aidx(t,b,j,27)] = hb;
          if (t < 511) p.A1[aidx(t+1,b,463+j,27)] = hb;
        } else {
          if (t < 511) p.A2[aidx(t+1,b,463+j,27)] = hb;
        }
        if (t == 511){ p.out[ohh + b*400 + j] = hh; p.out[occ + b*400 + j] = cn; }
      }
      if (grp == 0){
        __syncthreads();
        float* od = p.obuf + (size_t)(r%3)*9600 + (size_t)(s%5)*1920;
        #pragma unroll
        for (int i = 0; i < 2; ++i){
          int cell = tid + i*NT;
          if (cell < 1920){
            int b = cell & 63, n = cell >> 6;
            float sum = 0.f;
            #pragma unroll
            for (int jj = 0; jj < 16; ++jj)
              sum += hsh[jj][b] * wwin_l[n][jj];
            atomicAdd(&od[n*64 + b], sum);
          }
        }
      }
    }
    // grp0 zeroes its next-next o-slot (consumed at round r-1 -> safe), spread over 25 WGs
    if (grp == 0 && r <= 510 && tid < 384){
      float* oz = p.obuf + (size_t)((r+1)%3)*9600 + (size_t)s*384;
      __hip_atomic_store(&oz[tid], 0.f, __ATOMIC_RELAXED, __HIP_MEMORY_SCOPE_AGENT);
    }
    if (r < 514) gsyncx(fl, s, (unsigned)(r+1));
  }
}

// ---------------- output heads ----------------
__global__ __launch_bounds__(256) void kproj(P p){
  const int t = blockIdx.x >> 3, ns = blockIdx.x & 7;
  const int tid = threadIdx.x, lane = tid & 63, wave = tid >> 6;
  const int m = lane & 15, q = lane >> 4;
  float4v acc = {0.f,0.f,0.f,0.f};
  const size_t rowA = (size_t)t*64 + wave*16 + m;
  const u16* Bb = p.BP + ((size_t)ns*38)*512 + (size_t)lane*8;
  for (int kb = 0; kb < 38; ++kb){
    int k0 = kb*32 + q*8;
    const u16* src; int off;
    if (k0 < 400){ src = p.y0; off = k0; }
    else if (k0 < 800){ src = p.y1; off = k0 - 400; }
    else if (k0 < 1200){ src = p.y2; off = k0 - 800; }
    else { src = p.y0; off = 0; }     // B rows are zero for k>=1200
    short8 af = *reinterpret_cast<const short8*>(src + rowA*400 + off);
    short8 bf = *reinterpret_cast<const short8*>(Bb + (size_t)kb*512);
    acc = __builtin_amdgcn_mfma_f32_16x16x32_bf16(af, bf, acc, 0, 0, 0);
  }
  const int j = ns*16 + (lane & 15);
  const int bo = wave*16 + q*4;
  #pragma unroll
  for (int rr = 0; rr < 4; ++rr){
    float v = acc[rr];
    size_t ro = (size_t)t*64 + bo + rr;
    if (j < 40)        p.out[O_MEANS + ro*40 + j]        = v + p.bmu[j];
    else if (j < 80)   p.out[O_LS    + ro*40 + (j-40)]   = v + p.bls[j-40];
    else if (j < 100)  p.out[O_RHO   + ro*20 + (j-80)]   = tanhf(v + p.brho[j-80]);
    else if (j < 120)  p.out[O_PI    + ro*20 + (j-100)]  = v + p.bpi[j-100];
    else if (j == 120) p.out[O_EOS   + ro]               = v + p.beos[0];
  }
}

// ---------------- host ----------------
extern "C" void kernel_launch(void* const* d_in, const int* in_sizes, int n_in,
                              void* d_out, int out_size, void* d_ws, size_t ws_size,
                              hipStream_t stream){
  P p;
  p.strokes = (const float*)d_in[0];
  p.text    = (const int*)  d_in[1];
  p.tlen    = (const int*)  d_in[2];
  p.h0h = (const float*)d_in[3];  p.h0c = (const float*)d_in[4];
  p.h1h = (const float*)d_in[5];  p.h1c = (const float*)d_in[6];
  p.h2h = (const float*)d_in[7];  p.h2c = (const float*)d_in[8];
  p.pw  = (const float*)d_in[9];  p.pk  = (const float*)d_in[10];
  const float* Wih0 = (const float*)d_in[11]; const float* Whh0 = (const float*)d_in[12];
  p.bih0 = (const float*)d_in[13]; p.bhh0 = (const float*)d_in[14];
  const float* Wih1 = (const float*)d_in[15]; const float* Whh1 = (const float*)d_in[16];
  p.bih1 = (const float*)d_in[17]; p.bhh1 = (const float*)d_in[18];
  const float* Wih2 = (const float*)d_in[19]; const float* Whh2 = (const float*)d_in[20];
  p.bih2 = (const float*)d_in[21]; p.bhh2 = (const float*)d_in[22];
  p.Wwin = (const float*)d_in[23]; p.bwin = (const float*)d_in[24];
  const float* Wmu  = (const float*)d_in[25]; p.bmu  = (const float*)d_in[26];
  const float* Wls  = (const float*)d_in[27]; p.bls  = (const float*)d_in[28];
  const float* Wrho = (const float*)d_in[29]; p.brho = (const float*)d_in[30];
  const float* Wpi  = (const float*)d_in[31]; p.bpi  = (const float*)d_in[32];
  const float* Weos = (const float*)d_in[33]; p.beos = (const float*)d_in[34];
  p.out = (float*)d_out;

  char* w = (char*)d_ws; size_t off = 0;
  auto alloc = [&](size_t bytes)->void*{ void* r = w + off; off += (bytes + 511) & ~(size_t)511; return r; };
  p.B0  = (u16*)alloc((size_t)25*4*13*512*2);
  p.B1  = (u16*)alloc((size_t)25*4*27*512*2);
  p.B2  = (u16*)alloc((size_t)25*4*27*512*2);
  p.Bw0 = (u16*)alloc((size_t)25*4*2*512*2);
  p.BP  = (u16*)alloc((size_t)8*38*512*2);
  p.A0  = (u16*)alloc((size_t)512*4*13*512*2);
  p.A1  = (u16*)alloc((size_t)512*4*27*512*2);
  p.A2  = (u16*)alloc((size_t)512*4*27*512*2);
  p.y0  = (u16*)alloc((size_t)512*64*400*2);
  p.y1  = (u16*)alloc((size_t)512*64*400*2);
  p.y2  = (u16*)alloc((size_t)512*64*400*2);
  p.obuf= (float*)alloc((size_t)3*9600*4);
  p.bar = (unsigned*)alloc((size_t)4096*4);

  kpackB<<<dim3(2600), dim3(256), 0, stream>>>(Wih0, Whh0, p.B0, 13, 3,   63,  25*4*13*512);
  kpackB<<<dim3(5400), dim3(256), 0, stream>>>(Wih1, Whh1, p.B1, 27, 463, 463, 25*4*27*512);
  kpackB<<<dim3(5400), dim3(256), 0, stream>>>(Wih2, Whh2, p.B2, 27, 463, 463, 25*4*27*512);
  kpackBw<<<dim3(400), dim3(256), 0, stream>>>(Wih0, p.Bw0);
  kpackBP<<<dim3(608), dim3(256), 0, stream>>>(Wmu, Wls, Wrho, Wpi, Weos, p.BP);
  kfillA<<<dim3(4096), dim3(256), 0, stream>>>(p);
  kinit<<<dim3(429), dim3(256), 0, stream>>>(p);

  // 256 WGs at 1 WG/CU (LDS-bound) => exactly 32 per XCD; roles via XCC_ID.
  // 1024 threads/WG = 16 waves = 4 waves/SIMD: max TLP for latency hiding.
  kmain<<<dim3(256), dim3(NT), 0, stream>>>(p);

  kproj<<<dim3(4096), dim3(256), 0, stream>>>(p);
}

// Round 14
// 9612.765 us; speedup vs baseline: 1.0273x; 1.0273x over previous
//
#include <hip/hip_runtime.h>

typedef unsigned short u16;
typedef __attribute__((ext_vector_type(8))) short short8;   // 8 x bf16
typedef __attribute__((ext_vector_type(4))) float float4v;  // MFMA acc

#define NT 1024  // threads per worker WG: 16 waves = 4/SIMD (max TLP at 1 WG/CU)

// ---- output offsets (floats) ----
#define O_MEANS 0
#define O_LS    1310720
#define O_RHO   2621440
#define O_PI    3276800
#define O_EOS   3932160
#define O_H0H   3964928
#define O_H0C   3990528
#define O_H1H   4016128
#define O_H1C   4041728
#define O_H2H   4067328
#define O_H2C   4092928
#define O_PW    4118528
#define O_PK    4122368
#define O_AL    4123008

// bar layout (u32): [x*32] x=0..7 claim counters per XCD;
// group g region at 256+g*1024: arrival flags [i*32] i=0..24, flushed-gen [832].
#define GBASE(g)  (256 + (g)*1024)
#define FGOFF     832
#define SPIN_MAX  (1L<<19)

struct P {
  const float *strokes; const int *text; const int *tlen;
  const float *h0h,*h0c,*h1h,*h1c,*h2h,*h2c,*pw,*pk;
  const float *bih0,*bhh0,*bih1,*bhh1,*bih2,*bhh2;
  const float *Wwin,*bwin;
  const float *bmu,*bls,*brho,*bpi,*beos;
  u16 *B0,*B1,*B2,*Bw0,*BP;     // fragment-packed weights
  u16 *A0,*A1,*A2;              // fragment-packed activations per step
  u16 *y0,*y1,*y2;              // bf16 row-major hidden histories [T][64][400]
  float *obuf;                  // 3 rounds x 5 banks x [30][64] o-partials (atomic-only)
  unsigned *bar;                // claims + per-group flags + flushed gens
  float *out;
};

__device__ __forceinline__ u16 f2bf(float f){
  unsigned int x = __float_as_uint(f);
  unsigned int r = x + 0x7FFFu + ((x >> 16) & 1u);
  return (u16)(r >> 16);
}
// A-pack element (t, batch b, k) for a layer with KB k-blocks.
// block = (t*4 + b/16)*KB + k/32 ; inside: lane=((k>>3)&3)*16+(b&15), elem k&7
__device__ __forceinline__ size_t aidx(int t, int b, int k, int KB){
  return ((size_t)((t*4 + (b>>4))*KB + (k>>5)))*512
       + (size_t)(((((k>>3)&3)*16) + (b&15))*8 + (k&7));
}
__device__ __forceinline__ float sigm(float x){ return 1.f/(1.f+__expf(-x)); }
__device__ __forceinline__ float tanh_f(float x){ return 2.f/(1.f+__expf(-2.f*x)) - 1.f; }

// ---------------- weight packing ----------------
__global__ void kpackB(const float* __restrict__ Wih, const float* __restrict__ Whh,
                       u16* __restrict__ dst, int KB, int kx, int stride, int total){
  int tid = blockIdx.x*256 + threadIdx.x;
  if (tid >= total) return;
  int e = tid & 511, blk = tid >> 9;
  int kb = blk % KB, tile = (blk / KB) & 3, s = blk / (KB*4);
  int lane = e >> 3, j = e & 7;
  int q = lane >> 4, n = lane & 15;
  int k = kb*32 + q*8 + j;
  int col = s*16 + tile*4 + (n&3);
  int g = (n>>2)*400 + col;
  float v = 0.f;
  if (k < kx) v = Wih[(size_t)g*stride + k];
  else if (k < kx + 400) v = Whh[(size_t)g*400 + (k - kx)];
  dst[tid] = f2bf(v);
}

// inline-w weights for L0: [25][4][2][512], from Wih0 cols 3..62
__global__ void kpackBw(const float* __restrict__ Wih0, u16* __restrict__ dst){
  int tid = blockIdx.x*256 + threadIdx.x;
  if (tid >= 25*4*2*512) return;
  int e = tid & 511, blk = tid >> 9;
  int kb = blk & 1, tile = (blk>>1) & 3, s = blk >> 3;
  int lane = e >> 3, j = e & 7;
  int q = lane >> 4, n = lane & 15;
  int k = kb*32 + q*8 + j;
  int col = s*16 + tile*4 + (n&3);
  int g = (n>>2)*400 + col;
  dst[tid] = (k < 60) ? f2bf(Wih0[(size_t)g*63 + 3 + k]) : (u16)0;
}

// projection weights: cols 0..39 mu, 40..79 ls, 80..99 rho, 100..119 pi, 120 eos
__global__ void kpackBP(const float* __restrict__ Wmu, const float* __restrict__ Wls,
                        const float* __restrict__ Wrho, const float* __restrict__ Wpi,
                        const float* __restrict__ Weos, u16* __restrict__ dst){
  int tid = blockIdx.x*256 + threadIdx.x;
  if (tid >= 8*38*512) return;
  int e = tid & 511, blk = tid >> 9;
  int lane = e >> 3, j = e & 7;
  int ns = blk / 38, kb = blk % 38;
  int q = lane >> 4, n = lane & 15;
  int k = kb*32 + q*8 + j;
  int col = ns*16 + n;
  float v = 0.f;
  if (k < 1200){
    if (col < 40)       v = Wmu[(size_t)col*1200 + k];
    else if (col < 80)  v = Wls[(size_t)(col-40)*1200 + k];
    else if (col < 100) v = Wrho[(size_t)(col-80)*1200 + k];
    else if (col < 120) v = Wpi[(size_t)(col-100)*1200 + k];
    else if (col == 120) v = Weos[k];
  }
  dst[tid] = f2bf(v);
}

// strokes rows + zero pads for all t (ws is 0xAA-poisoned every run)
__global__ void kfillA(P p){
  int tid = blockIdx.x*256 + threadIdx.x;
  if (tid >= 512*64*32) return;
  int it = tid & 31; int rr = tid >> 5; int b = rr & 63; int t = rr >> 6;
  const float* sx = p.strokes + ((size_t)t*64 + b)*3;
  if (it < 3)        p.A0[aidx(t,b,it,13)] = f2bf(sx[it]);
  else if (it < 16)  p.A0[aidx(t,b,400+it,13)] = 0;          // pads 403..415
  else if (it < 19)  p.A1[aidx(t,b,460+(it-16),27)] = f2bf(sx[it-16]);
  else if (it == 19) p.A1[aidx(t,b,863,27)] = 0;
  else if (it < 23)  p.A2[aidx(t,b,460+(it-20),27)] = f2bf(sx[it-20]);
  else if (it == 23) p.A2[aidx(t,b,863,27)] = 0;
}

// initial states + obuf/claims/flags zero
__global__ void kinit(P p){
  int tid = blockIdx.x*256 + threadIdx.x;
  if (tid < 25600){ int b=tid/400, j=tid%400; p.A0[aidx(0,b,3+j,13)] = f2bf(p.h0h[tid]); }
  else if (tid < 51200){ int i=tid-25600; int b=i/400, j=i%400; p.A1[aidx(0,b,463+j,27)] = f2bf(p.h1h[i]); }
  else if (tid < 76800){ int i=tid-51200; int b=i/400, j=i%400; p.A2[aidx(0,b,463+j,27)] = f2bf(p.h2h[i]); }
  else if (tid < 105600){ p.obuf[tid-76800] = 0.f; }
  else if (tid < 109696){ p.bar[tid-105600] = 0u; }
}

// ---------------- intra-XCD 25-WG barrier, fence-free, 1-hop (R11-proven) ----------------
__device__ __forceinline__ void gsyncx(unsigned* fl, int s, unsigned target){
  __threadfence_block();   // drain this wave's stores into the shared L2
  __syncthreads();         // all waves drained
  if (threadIdx.x == 0)
    __hip_atomic_store(&fl[s*32], target, __ATOMIC_RELAXED, __HIP_MEMORY_SCOPE_AGENT);
  if (threadIdx.x < 25){
    long c = 0;
    while (__hip_atomic_load(&fl[threadIdx.x*32], __ATOMIC_RELAXED, __HIP_MEMORY_SCOPE_AGENT) < target){
      __builtin_amdgcn_s_sleep(1);
      if (++c > SPIN_MAX) break;   // failsafe: wrong answer, never a hang
    }
  }
  __syncthreads();
}

// wait for a producer group's FLUSHED generation (pre-satisfied by pipeline lag)
__device__ __forceinline__ void waitgen(const unsigned* gw, unsigned target){
  if (threadIdx.x == 0){
    long c = 0;
    while (__hip_atomic_load(gw, __ATOMIC_RELAXED, __HIP_MEMORY_SCOPE_AGENT) < target){
      __builtin_amdgcn_s_sleep(1);
      if (++c > SPIN_MAX) break;
    }
  }
  __syncthreads();
}

// ---------------- main persistent kernel: 3 XCD-local groups, 16 waves/WG ----------------
// 256 WGs (1 WG/CU by LDS => 32/XCD). Roles via XCC_ID claim. Wave w owns
// (b-quadrant bq = w&3, tile th = w>>2) -> exactly 1 column tile each.
// __launch_bounds__(1024, 4): 4 min-waves/EU caps VGPR at 128 — exactly the
// 4-wave/SIMD budget. R13's (1024,1) let the compiler clamp to 64 VGPR and
// spill 1.2 GB/dispatch to scratch (WRITE_SIZE counter-verified).
__global__ __launch_bounds__(NT, 4) void kmain(P p){
  const int tid = threadIdx.x;
  const int lane = tid & 63, wave = tid >> 6;
  const int bq = wave & 3, th = wave >> 2;

  __shared__ int role2[2];
  if (tid == 0){
    unsigned x;
    asm volatile("s_getreg_b32 %0, hwreg(HW_REG_XCC_ID, 0, 4)" : "=s"(x));
    x &= 7u;
    unsigned sl = atomicAdd(&p.bar[x*32], 1u);
    role2[0] = (int)x; role2[1] = (int)sl;
  }
  __syncthreads();
  const int grp = role2[0];
  const int s   = role2[1];
  if (grp > 2 || s > 25) return;
  unsigned* fl = p.bar + GBASE(grp);

  if (s == 25){                       // flusher: wbl2 this XCD's L2 per round
    if (grp == 2) return;             // nobody consumes grp2's flush
    if (tid < 25){
      unsigned* fg = fl + FGOFF;
      for (unsigned rr = 1; rr <= 514; ++rr){
        long c = 0;
        while (__hip_atomic_load(&fl[tid*32], __ATOMIC_RELAXED, __HIP_MEMORY_SCOPE_AGENT) < rr){
          __builtin_amdgcn_s_sleep(2);
          if (++c > SPIN_MAX) break;
        }
        if (tid == 0){
          __builtin_amdgcn_fence(__ATOMIC_RELEASE, "agent");   // waitcnt + wbl2
          __hip_atomic_store(fg, rr, __ATOMIC_RELAXED, __HIP_MEMORY_SCOPE_AGENT);
        }
      }
    }
    return;
  }

  const int lag = (grp == 0) ? 0 : (grp + 1);   // 0,2,3

  __shared__ u16  wB[55296];         // 110592 B weight slice (+ grp0 overlay)
  __shared__ float ldsg[64][65];     // gate tile [b][4 tiles *16 cols]
  __shared__ float clds[16][64];     // persistent cell state [jj][b]
  __shared__ float bsum[64];         // bias sums [jj*4+gate], this slice

  // grp0 overlays in wB[30720..55295] (49152 B available, 46328 used)
  u16* wBw = wB + 26624;                                   // 8 KB inline-w weights
  char* exb = (char*)(wB + 30720);
  float (*hsh)[64]  = (float (*)[64])(exb);                //  4096 B  h0 stage
  float (*wacc)[64] = (float (*)[64])(exb + 4096);         // 15360 B  w accum
  u16   (*wbf)[80]  = (u16   (*)[80])(exb + 19456);        // 10240 B  w A-operand
  float (*klds)[10] = (float (*)[10])(exb + 29696);        //  2560 B  kappa
  float (*ash)[10]  = (float (*)[10])(exb + 32256);
  float (*bsh)[10]  = (float (*)[10])(exb + 34816);
  float (*ksh)[10]  = (float (*)[10])(exb + 37376);        // end 39936
  float (*wwin_l)[16] = (float (*)[16])(exb + 39936);      //  1920 B Wwin slice
  unsigned char* text_l = (unsigned char*)(exb + 41856);   //  4096 B text (u8)
  int*   tlen_l = (int*)(exb + 45952);                     //   256 B
  float* bwin_l = (float*)(exb + 46208);                   //   120 B, end 46328

  const u16 *Ap; u16 *yr;
  const float *bi, *bh, *cin; int ohh, occ;
  if (grp == 0){ Ap=p.A0; yr=p.y0; bi=p.bih0; bh=p.bhh0; cin=p.h0c; ohh=O_H0H; occ=O_H0C; }
  else if (grp == 1){ Ap=p.A1; yr=p.y1; bi=p.bih1; bh=p.bhh1; cin=p.h1c; ohh=O_H1H; occ=O_H1C; }
  else { Ap=p.A2; yr=p.y2; bi=p.bih2; bh=p.bhh2; cin=p.h2c; ohh=O_H2H; occ=O_H2C; }

  // ---- stage weight slice into LDS (once) ----
  {
    const u16* gsrc; int cnt;
    if (grp == 0){ gsrc = p.B0 + (size_t)s*26624; cnt = 26624; }
    else if (grp == 1){ gsrc = p.B1 + (size_t)s*55296; cnt = 55296; }
    else { gsrc = p.B2 + (size_t)s*55296; cnt = 55296; }
    for (int i = tid*8; i < cnt; i += NT*8)
      *reinterpret_cast<short8*>(&wB[i]) = *reinterpret_cast<const short8*>(gsrc + i);
    if (grp == 0){
      const u16* gw = p.Bw0 + (size_t)s*4096;
      if (tid*8 < 4096)
        *reinterpret_cast<short8*>(wBw + tid*8) = *reinterpret_cast<const short8*>(gw + tid*8);
    }
  }

  if (tid < 1024){
    int jj = tid >> 6, b = tid & 63;
    clds[jj][b] = cin[b*400 + s*16 + jj];
  }
  if (tid < 64){
    int jj = tid >> 2, gg = tid & 3;
    bsum[tid] = bi[gg*400 + s*16 + jj] + bh[gg*400 + s*16 + jj];
  }
  if (grp == 0){
    if (tid < 640) klds[tid/10][tid%10] = p.pk[tid];
    for (int cell = tid; cell < 64*80; cell += NT){
      int b = cell/80, k = cell%80;
      wbf[b][k] = (k < 60) ? f2bf(p.pw[b*60 + k]) : (u16)0;
    }
    if (tid < 480) wwin_l[tid>>4][tid&15] = p.Wwin[(tid>>4)*400 + s*16 + (tid&15)];
    for (int cell = tid; cell < 4096; cell += NT)
      text_l[cell] = (unsigned char)p.text[cell];
    if (tid < 64) tlen_l[tid] = p.tlen[tid];
    if (tid < 30) bwin_l[tid] = p.bwin[tid];
  }
  __syncthreads();

  for (int r = 0; r < 515; ++r){
    const int t = r - lag;

    // ---- cross-group ordering via FLUSHED gens (pre-satisfied by lag) ----
    if (grp == 1 && r >= 2 && r <= 513) waitgen(p.bar + GBASE(0) + FGOFF, (unsigned)r);
    if (grp == 2 && r >= 3 && r <= 514) waitgen(p.bar + GBASE(1) + FGOFF, (unsigned)r);

    // ---- grp0: hoist obuf bank loads then A0 frags ----
    float ovs[2][5];
    if (grp == 0 && r >= 1 && r <= 512){
      const float* ob = p.obuf + (size_t)((r-1)%3)*9600;
      #pragma unroll
      for (int i = 0; i < 2; ++i){
        int cell = tid + i*NT;
        if (cell < 1920){
          #pragma unroll
          for (int bk = 0; bk < 5; ++bk)
            ovs[i][bk] = __hip_atomic_load(&ob[bk*1920 + cell], __ATOMIC_RELAXED, __HIP_MEMORY_SCOPE_AGENT);
        }
      }
    }
    short8 a0r[13];
    if (grp == 0 && t < 512){
      const u16* Ab = p.A0 + ((size_t)(t*4 + bq)*13)*512 + (size_t)lane*8;
      #pragma unroll
      for (int kb = 0; kb < 13; ++kb)
        a0r[kb] = *reinterpret_cast<const short8*>(Ab + (size_t)kb*512);
    }

    // ---- window finalize for t = r-1 (replicated across the 25 L0 WGs) ----
    if (grp == 0 && r >= 1 && r <= 512){
      const int tw = r - 1;
      #pragma unroll
      for (int i = 0; i < 2; ++i){
        int cell = tid + i*NT;
        if (cell < 1920){
          int b = cell & 63, n = cell >> 6;
          float o = ovs[i][0]+ovs[i][1]+ovs[i][2]+ovs[i][3]+ovs[i][4] + bwin_l[n];
          if (n < 10) ash[b][n] = __expf(o);
          else if (n < 20) bsh[b][n-10] = __expf(o);
          else { float kn = klds[b][n-20] + 0.05f*__expf(o); klds[b][n-20] = kn; ksh[b][n-20] = kn; }
        }
      }
      for (int cell = tid; cell < 3840; cell += NT) ((float*)wacc)[cell] = 0.f;
      __syncthreads();
      {
        // thread owns b = tid>>4, u = (tid&15)*4 .. +3 -> Gaussian params in regs
        const int b = tid >> 4, u0 = (tid & 15) * 4;
        const int tl = tlen_l[b];
        float ph[4] = {0.f, 0.f, 0.f, 0.f};
        if (u0 < tl){
          float av[10], bv[10], kv[10];
          #pragma unroll
          for (int n = 0; n < 10; ++n){ av[n]=ash[b][n]; bv[n]=bsh[b][n]; kv[n]=ksh[b][n]; }
          #pragma unroll
          for (int j = 0; j < 4; ++j){
            int u = u0 + j;
            if (u < tl){
              float phi = 0.f;
              #pragma unroll
              for (int n = 0; n < 10; ++n){
                float d = kv[n] - (float)u;
                phi += av[n]*__expf(-bv[n]*d*d);
              }
              ph[j] = phi;
              atomicAdd(&wacc[text_l[b*64 + u]][b], phi);
            }
          }
        }
        #pragma unroll
        for (int j = 0; j < 4; ++j){
          int cell = tid*4 + j;
          if (((cell*25) >> 12) == s)   // O_AL spread over 25 WGs
            p.out[O_AL + ((size_t)tw*64 + b)*64 + u0 + j] = ph[j];
        }
      }
      __syncthreads();
      for (int cell = tid; cell < 3840; cell += NT){
        int b = cell & 63, l = cell >> 6;
        u16 wv = f2bf(wacc[l][b]);
        wbf[b][l] = wv;
        if (s == 1) p.A1[aidx(tw,b,400+l,27)] = wv;
        if (s == 2) p.A2[aidx(tw,b,400+l,27)] = wv;
        if (s == 0 && tw == 511) p.out[O_PW + b*60 + l] = wacc[l][b];
      }
      if (s == 0 && tw == 511 && tid < 640) p.out[O_PK + tid] = klds[tid/10][tid%10];
      __syncthreads();
    }

    // ---- gate GEMM + LSTM pointwise ----
    if (t >= 0 && t < 512){
      float4v acc = {0.f,0.f,0.f,0.f};
      if (grp == 0){
        #pragma unroll
        for (int kb = 0; kb < 13; ++kb){
          short8 bf = *reinterpret_cast<const short8*>(wB + (size_t)(th*13 + kb)*512 + (size_t)lane*8);
          acc = __builtin_amdgcn_mfma_f32_16x16x32_bf16(a0r[kb], bf, acc, 0, 0, 0);
        }
        const int m = lane & 15, q = (lane >> 4) & 3;
        #pragma unroll
        for (int kb = 0; kb < 2; ++kb){
          short8 af = *reinterpret_cast<const short8*>(&wbf[bq*16 + m][kb*32 + q*8]);
          short8 bf = *reinterpret_cast<const short8*>(wBw + (size_t)((th*2 + kb))*512 + (size_t)lane*8);
          acc = __builtin_amdgcn_mfma_f32_16x16x32_bf16(af, bf, acc, 0, 0, 0);
        }
      } else {
        const u16* Ab = Ap + ((size_t)(t*4 + bq)*27)*512 + (size_t)lane*8;
        #pragma unroll
        for (int ch = 0; ch < 3; ++ch){      // 3x9 chunks: VGPR-safe at 4 waves/SIMD
          short8 a1r[9];
          #pragma unroll
          for (int kb = 0; kb < 9; ++kb)
            a1r[kb] = *reinterpret_cast<const short8*>(Ab + (size_t)(ch*9 + kb)*512);
          #pragma unroll
          for (int kb = 0; kb < 9; ++kb){
            short8 bf = *reinterpret_cast<const short8*>(wB + (size_t)(th*27 + ch*9 + kb)*512 + (size_t)lane*8);
            acc = __builtin_amdgcn_mfma_f32_16x16x32_bf16(a1r[kb], bf, acc, 0, 0, 0);
          }
        }
      }
      {
        const int c = lane & 15, rb = bq*16 + ((lane>>4)<<2);
        #pragma unroll
        for (int rr2 = 0; rr2 < 4; ++rr2)
          ldsg[rb+rr2][th*16 + c] = acc[rr2];
      }
      __syncthreads();
      if (tid < 1024){
        int jj = tid >> 6, b = tid & 63;
        int j = s*16 + jj, tt = jj >> 2, jo = jj & 3;
        float gi = ldsg[b][tt*16 +      jo] + bsum[jj*4 + 0];
        float gf = ldsg[b][tt*16 +  4 + jo] + bsum[jj*4 + 1];
        float gg = ldsg[b][tt*16 +  8 + jo] + bsum[jj*4 + 2];
        float go = ldsg[b][tt*16 + 12 + jo] + bsum[jj*4 + 3];
        float cp = clds[jj][b];
        float cn = sigm(gf)*cp + sigm(gi)*tanh_f(gg);
        float hh = sigm(go)*tanh_f(cn);
        clds[jj][b] = cn;
        u16 hb = f2bf(hh);
        yr[((size_t)t*64 + b)*400 + j] = hb;
        if (grp == 0){
          p.A1[aidx(t,b,j,27)] = hb;
          if (t < 511) p.A0[aidx(t+1,b,3+j,13)] = hb;
          hsh[jj][b] = hh;
        } else if (grp == 1){
          p.A2[aidx(t,b,j,27)] = hb;
          if (t < 511) p.A1[aidx(t+1,b,463+j,27)] = hb;
        } else {
          if (t < 511) p.A2[aidx(t+1,b,463+j,27)] = hb;
        }
        if (t == 511){ p.out[ohh + b*400 + j] = hh; p.out[occ + b*400 + j] = cn; }
      }
      if (grp == 0){
        __syncthreads();
        float* od = p.obuf + (size_t)(r%3)*9600 + (size_t)(s%5)*1920;
        #pragma unroll
        for (int i = 0; i < 2; ++i){
          int cell = tid + i*NT;
          if (cell < 1920){
            int b = cell & 63, n = cell >> 6;
            float sum = 0.f;
            #pragma unroll
            for (int jj = 0; jj < 16; ++jj)
              sum += hsh[jj][b] * wwin_l[n][jj];
            atomicAdd(&od[n*64 + b], sum);
          }
        }
      }
    }
    // grp0 zeroes its next-next o-slot (consumed at round r-1 -> safe), spread over 25 WGs
    if (grp == 0 && r <= 510 && tid < 384){
      float* oz = p.obuf + (size_t)((r+1)%3)*9600 + (size_t)s*384;
      __hip_atomic_store(&oz[tid], 0.f, __ATOMIC_RELAXED, __HIP_MEMORY_SCOPE_AGENT);
    }
    if (r < 514) gsyncx(fl, s, (unsigned)(r+1));
  }
}

// ---------------- output heads ----------------
__global__ __launch_bounds__(256) void kproj(P p){
  const int t = blockIdx.x >> 3, ns = blockIdx.x & 7;
  const int tid = threadIdx.x, lane = tid & 63, wave = tid >> 6;
  const int m = lane & 15, q = lane >> 4;
  float4v acc = {0.f,0.f,0.f,0.f};
  const size_t rowA = (size_t)t*64 + wave*16 + m;
  const u16* Bb = p.BP + ((size_t)ns*38)*512 + (size_t)lane*8;
  for (int kb = 0; kb < 38; ++kb){
    int k0 = kb*32 + q*8;
    const u16* src; int off;
    if (k0 < 400){ src = p.y0; off = k0; }
    else if (k0 < 800){ src = p.y1; off = k0 - 400; }
    else if (k0 < 1200){ src = p.y2; off = k0 - 800; }
    else { src = p.y0; off = 0; }     // B rows are zero for k>=1200
    short8 af = *reinterpret_cast<const short8*>(src + rowA*400 + off);
    short8 bf = *reinterpret_cast<const short8*>(Bb + (size_t)kb*512);
    acc = __builtin_amdgcn_mfma_f32_16x16x32_bf16(af, bf, acc, 0, 0, 0);
  }
  const int j = ns*16 + (lane & 15);
  const int bo = wave*16 + q*4;
  #pragma unroll
  for (int rr = 0; rr < 4; ++rr){
    float v = acc[rr];
    size_t ro = (size_t)t*64 + bo + rr;
    if (j < 40)        p.out[O_MEANS + ro*40 + j]        = v + p.bmu[j];
    else if (j < 80)   p.out[O_LS    + ro*40 + (j-40)]   = v + p.bls[j-40];
    else if (j < 100)  p.out[O_RHO   + ro*20 + (j-80)]   = tanhf(v + p.brho[j-80]);
    else if (j < 120)  p.out[O_PI    + ro*20 + (j-100)]  = v + p.bpi[j-100];
    else if (j == 120) p.out[O_EOS   + ro]               = v + p.beos[0];
  }
}

// ---------------- host ----------------
extern "C" void kernel_launch(void* const* d_in, const int* in_sizes, int n_in,
                              void* d_out, int out_size, void* d_ws, size_t ws_size,
                              hipStream_t stream){
  P p;
  p.strokes = (const float*)d_in[0];
  p.text    = (const int*)  d_in[1];
  p.tlen    = (const int*)  d_in[2];
  p.h0h = (const float*)d_in[3];  p.h0c = (const float*)d_in[4];
  p.h1h = (const float*)d_in[5];  p.h1c = (const float*)d_in[6];
  p.h2h = (const float*)d_in[7];  p.h2c = (const float*)d_in[8];
  p.pw  = (const float*)d_in[9];  p.pk  = (const float*)d_in[10];
  const float* Wih0 = (const float*)d_in[11]; const float* Whh0 = (const float*)d_in[12];
  p.bih0 = (const float*)d_in[13]; p.bhh0 = (const float*)d_in[14];
  const float* Wih1 = (const float*)d_in[15]; const float* Whh1 = (const float*)d_in[16];
  p.bih1 = (const float*)d_in[17]; p.bhh1 = (const float*)d_in[18];
  const float* Wih2 = (const float*)d_in[19]; const float* Whh2 = (const float*)d_in[20];
  p.bih2 = (const float*)d_in[21]; p.bhh2 = (const float*)d_in[22];
  p.Wwin = (const float*)d_in[23]; p.bwin = (const float*)d_in[24];
  const float* Wmu  = (const float*)d_in[25]; p.bmu  = (const float*)d_in[26];
  const float* Wls  = (const float*)d_in[27]; p.bls  = (const float*)d_in[28];
  const float* Wrho = (const float*)d_in[29]; p.brho = (const float*)d_in[30];
  const float* Wpi  = (const float*)d_in[31]; p.bpi  = (const float*)d_in[32];
  const float* Weos = (const float*)d_in[33]; p.beos = (const float*)d_in[34];
  p.out = (float*)d_out;

  char* w = (char*)d_ws; size_t off = 0;
  auto alloc = [&](size_t bytes)->void*{ void* r = w + off; off += (bytes + 511) & ~(size_t)511; return r; };
  p.B0  = (u16*)alloc((size_t)25*4*13*512*2);
  p.B1  = (u16*)alloc((size_t)25*4*27*512*2);
  p.B2  = (u16*)alloc((size_t)25*4*27*512*2);
  p.Bw0 = (u16*)alloc((size_t)25*4*2*512*2);
  p.BP  = (u16*)alloc((size_t)8*38*512*2);
  p.A0  = (u16*)alloc((size_t)512*4*13*512*2);
  p.A1  = (u16*)alloc((size_t)512*4*27*512*2);
  p.A2  = (u16*)alloc((size_t)512*4*27*512*2);
  p.y0  = (u16*)alloc((size_t)512*64*400*2);
  p.y1  = (u16*)alloc((size_t)512*64*400*2);
  p.y2  = (u16*)alloc((size_t)512*64*400*2);
  p.obuf= (float*)alloc((size_t)3*9600*4);
  p.bar = (unsigned*)alloc((size_t)4096*4);

  kpackB<<<dim3(2600), dim3(256), 0, stream>>>(Wih0, Whh0, p.B0, 13, 3,   63,  25*4*13*512);
  kpackB<<<dim3(5400), dim3(256), 0, stream>>>(Wih1, Whh1, p.B1, 27, 463, 463, 25*4*27*512);
  kpackB<<<dim3(5400), dim3(256), 0, stream>>>(Wih2, Whh2, p.B2, 27, 463, 463, 25*4*27*512);
  kpackBw<<<dim3(400), dim3(256), 0, stream>>>(Wih0, p.Bw0);
  kpackBP<<<dim3(608), dim3(256), 0, stream>>>(Wmu, Wls, Wrho, Wpi, Weos, p.BP);
  kfillA<<<dim3(4096), dim3(256), 0, stream>>>(p);
  kinit<<<dim3(429), dim3(256), 0, stream>>>(p);

  // 256 WGs at 1 WG/CU (LDS-bound) => exactly 32 per XCD; roles via XCC_ID.
  // 1024 threads/WG = 16 waves = 4 waves/SIMD; VGPR capped at 128 (no spill).
  kmain<<<dim3(256), dim3(NT), 0, stream>>>(p);

  kproj<<<dim3(4096), dim3(256), 0, stream>>>(p);
}

// Round 15
// 5721.049 us; speedup vs baseline: 1.7262x; 1.6802x over previous
//
#include <hip/hip_runtime.h>

typedef unsigned short u16;
typedef __attribute__((ext_vector_type(8))) short short8;   // 8 x bf16
typedef __attribute__((ext_vector_type(4))) float float4v;  // MFMA acc

#define NT 512   // threads per worker WG: 8 waves = 2/SIMD (R12-proven; NT=1024 spills, see R13/R14)

// ---- output offsets (floats) ----
#define O_MEANS 0
#define O_LS    1310720
#define O_RHO   2621440
#define O_PI    3276800
#define O_EOS   3932160
#define O_H0H   3964928
#define O_H0C   3990528
#define O_H1H   4016128
#define O_H1C   4041728
#define O_H2H   4067328
#define O_H2C   4092928
#define O_PW    4118528
#define O_PK    4122368
#define O_AL    4123008

// bar layout (u32): [x*32] x=0..7 claim counters per XCD;
// group g region at 256+g*1024: arrival flags [i*32] i=0..24, flushed-gen [832].
#define GBASE(g)  (256 + (g)*1024)
#define FGOFF     832
#define SPIN_MAX  (1L<<19)

struct P {
  const float *strokes; const int *text; const int *tlen;
  const float *h0h,*h0c,*h1h,*h1c,*h2h,*h2c,*pw,*pk;
  const float *bih0,*bhh0,*bih1,*bhh1,*bih2,*bhh2;
  const float *Wwin,*bwin;
  const float *bmu,*bls,*brho,*bpi,*beos;
  u16 *B0,*B1,*B2,*Bw0,*BP;     // fragment-packed weights
  u16 *A0,*A1,*A2;              // fragment-packed activations per step
  u16 *y0,*y1,*y2;              // bf16 row-major hidden histories [T][64][400]
  float *obuf;                  // 3 rounds x 5 banks x [30][64] o-partials (atomic-only)
  unsigned *bar;                // claims + per-group flags + flushed gens
  float *out;
};

__device__ __forceinline__ u16 f2bf(float f){
  unsigned int x = __float_as_uint(f);
  unsigned int r = x + 0x7FFFu + ((x >> 16) & 1u);
  return (u16)(r >> 16);
}
// A-pack element (t, batch b, k) for a layer with KB k-blocks.
// block = (t*4 + b/16)*KB + k/32 ; inside: lane=((k>>3)&3)*16+(b&15), elem k&7
__device__ __forceinline__ size_t aidx(int t, int b, int k, int KB){
  return ((size_t)((t*4 + (b>>4))*KB + (k>>5)))*512
       + (size_t)(((((k>>3)&3)*16) + (b&15))*8 + (k&7));
}
__device__ __forceinline__ float sigm(float x){ return 1.f/(1.f+__expf(-x)); }
__device__ __forceinline__ float tanh_f(float x){ return 2.f/(1.f+__expf(-2.f*x)) - 1.f; }

// ---------------- weight packing ----------------
__global__ void kpackB(const float* __restrict__ Wih, const float* __restrict__ Whh,
                       u16* __restrict__ dst, int KB, int kx, int stride, int total){
  int tid = blockIdx.x*256 + threadIdx.x;
  if (tid >= total) return;
  int e = tid & 511, blk = tid >> 9;
  int kb = blk % KB, tile = (blk / KB) & 3, s = blk / (KB*4);
  int lane = e >> 3, j = e & 7;
  int q = lane >> 4, n = lane & 15;
  int k = kb*32 + q*8 + j;
  int col = s*16 + tile*4 + (n&3);
  int g = (n>>2)*400 + col;
  float v = 0.f;
  if (k < kx) v = Wih[(size_t)g*stride + k];
  else if (k < kx + 400) v = Whh[(size_t)g*400 + (k - kx)];
  dst[tid] = f2bf(v);
}

// inline-w weights for L0: [25][4][2][512], from Wih0 cols 3..62
__global__ void kpackBw(const float* __restrict__ Wih0, u16* __restrict__ dst){
  int tid = blockIdx.x*256 + threadIdx.x;
  if (tid >= 25*4*2*512) return;
  int e = tid & 511, blk = tid >> 9;
  int kb = blk & 1, tile = (blk>>1) & 3, s = blk >> 3;
  int lane = e >> 3, j = e & 7;
  int q = lane >> 4, n = lane & 15;
  int k = kb*32 + q*8 + j;
  int col = s*16 + tile*4 + (n&3);
  int g = (n>>2)*400 + col;
  dst[tid] = (k < 60) ? f2bf(Wih0[(size_t)g*63 + 3 + k]) : (u16)0;
}

// projection weights: cols 0..39 mu, 40..79 ls, 80..99 rho, 100..119 pi, 120 eos
__global__ void kpackBP(const float* __restrict__ Wmu, const float* __restrict__ Wls,
                        const float* __restrict__ Wrho, const float* __restrict__ Wpi,
                        const float* __restrict__ Weos, u16* __restrict__ dst){
  int tid = blockIdx.x*256 + threadIdx.x;
  if (tid >= 8*38*512) return;
  int e = tid & 511, blk = tid >> 9;
  int lane = e >> 3, j = e & 7;
  int ns = blk / 38, kb = blk % 38;
  int q = lane >> 4, n = lane & 15;
  int k = kb*32 + q*8 + j;
  int col = ns*16 + n;
  float v = 0.f;
  if (k < 1200){
    if (col < 40)       v = Wmu[(size_t)col*1200 + k];
    else if (col < 80)  v = Wls[(size_t)(col-40)*1200 + k];
    else if (col < 100) v = Wrho[(size_t)(col-80)*1200 + k];
    else if (col < 120) v = Wpi[(size_t)(col-100)*1200 + k];
    else if (col == 120) v = Weos[k];
  }
  dst[tid] = f2bf(v);
}

// strokes rows + zero pads for all t (ws is 0xAA-poisoned every run)
__global__ void kfillA(P p){
  int tid = blockIdx.x*256 + threadIdx.x;
  if (tid >= 512*64*32) return;
  int it = tid & 31; int rr = tid >> 5; int b = rr & 63; int t = rr >> 6;
  const float* sx = p.strokes + ((size_t)t*64 + b)*3;
  if (it < 3)        p.A0[aidx(t,b,it,13)] = f2bf(sx[it]);
  else if (it < 16)  p.A0[aidx(t,b,400+it,13)] = 0;          // pads 403..415
  else if (it < 19)  p.A1[aidx(t,b,460+(it-16),27)] = f2bf(sx[it-16]);
  else if (it == 19) p.A1[aidx(t,b,863,27)] = 0;
  else if (it < 23)  p.A2[aidx(t,b,460+(it-20),27)] = f2bf(sx[it-20]);
  else if (it == 23) p.A2[aidx(t,b,863,27)] = 0;
}

// initial states + obuf/claims/flags zero
__global__ void kinit(P p){
  int tid = blockIdx.x*256 + threadIdx.x;
  if (tid < 25600){ int b=tid/400, j=tid%400; p.A0[aidx(0,b,3+j,13)] = f2bf(p.h0h[tid]); }
  else if (tid < 51200){ int i=tid-25600; int b=i/400, j=i%400; p.A1[aidx(0,b,463+j,27)] = f2bf(p.h1h[i]); }
  else if (tid < 76800){ int i=tid-51200; int b=i/400, j=i%400; p.A2[aidx(0,b,463+j,27)] = f2bf(p.h2h[i]); }
  else if (tid < 105600){ p.obuf[tid-76800] = 0.f; }
  else if (tid < 109696){ p.bar[tid-105600] = 0u; }
}

// ---------------- intra-XCD 25-WG barrier, fence-free, 1-hop (R11-proven) ----------------
__device__ __forceinline__ void gsyncx(unsigned* fl, int s, unsigned target){
  __threadfence_block();   // drain this wave's stores into the shared L2
  __syncthreads();         // all waves drained
  if (threadIdx.x == 0)
    __hip_atomic_store(&fl[s*32], target, __ATOMIC_RELAXED, __HIP_MEMORY_SCOPE_AGENT);
  if (threadIdx.x < 25){
    long c = 0;
    while (__hip_atomic_load(&fl[threadIdx.x*32], __ATOMIC_RELAXED, __HIP_MEMORY_SCOPE_AGENT) < target){
      __builtin_amdgcn_s_sleep(1);
      if (++c > SPIN_MAX) break;   // failsafe: wrong answer, never a hang
    }
  }
  __syncthreads();
}

// wait for a producer group's FLUSHED generation (pre-satisfied by pipeline lag)
__device__ __forceinline__ void waitgen(const unsigned* gw, unsigned target){
  if (threadIdx.x == 0){
    long c = 0;
    while (__hip_atomic_load(gw, __ATOMIC_RELAXED, __HIP_MEMORY_SCOPE_AGENT) < target){
      __builtin_amdgcn_s_sleep(1);
      if (++c > SPIN_MAX) break;
    }
  }
  __syncthreads();
}

// ---------------- main persistent kernel: 3 XCD-local groups, 8 waves/WG ----------------
// 256 WGs (1 WG/CU by LDS => 32/XCD). Roles via XCC_ID claim. Wave w owns
// (b-quadrant bq = w&3, tile-pair th = w>>2) -> 2 column tiles each.
// __launch_bounds__(512, 2): cap VGPR at 256 (true occupancy: 2 waves/SIMD).
// NT=1024 is poisoned: compiler allocates 64 VGPR regardless of bounds and
// spills 1.2 GB/dispatch (R13/R14 counter-verified).
__global__ __launch_bounds__(NT, 2) void kmain(P p){
  const int tid = threadIdx.x;
  const int lane = tid & 63, wave = tid >> 6;
  const int bq = wave & 3, th = wave >> 2;

  __shared__ int role2[2];
  if (tid == 0){
    unsigned x;
    asm volatile("s_getreg_b32 %0, hwreg(HW_REG_XCC_ID, 0, 4)" : "=s"(x));
    x &= 7u;
    unsigned sl = atomicAdd(&p.bar[x*32], 1u);
    role2[0] = (int)x; role2[1] = (int)sl;
  }
  __syncthreads();
  const int grp = role2[0];
  const int s   = role2[1];
  if (grp > 2 || s > 25) return;
  unsigned* fl = p.bar + GBASE(grp);

  if (s == 25){                       // flusher: wbl2 this XCD's L2 per round
    if (grp == 2) return;             // nobody consumes grp2's flush
    if (tid < 25){
      unsigned* fg = fl + FGOFF;
      for (unsigned rr = 1; rr <= 514; ++rr){
        long c = 0;
        while (__hip_atomic_load(&fl[tid*32], __ATOMIC_RELAXED, __HIP_MEMORY_SCOPE_AGENT) < rr){
          __builtin_amdgcn_s_sleep(2);
          if (++c > SPIN_MAX) break;
        }
        if (tid == 0){
          __builtin_amdgcn_fence(__ATOMIC_RELEASE, "agent");   // waitcnt + wbl2
          __hip_atomic_store(fg, rr, __ATOMIC_RELAXED, __HIP_MEMORY_SCOPE_AGENT);
        }
      }
    }
    return;
  }

  const int lag = (grp == 0) ? 0 : (grp + 1);   // 0,2,3

  __shared__ u16  wB[55296];         // 110592 B weight slice (+ grp0 overlay)
  __shared__ float ldsg[64][65];     // gate tile [b][4 tiles *16 cols]
  __shared__ float clds[16][64];     // persistent cell state [jj][b]
  __shared__ float bsum[64];         // bias sums [jj*4+gate], this slice

  // grp0 overlays in wB[30720..55295] (49152 B available, 46328 used)
  u16* wBw = wB + 26624;                                   // 8 KB inline-w weights
  char* exb = (char*)(wB + 30720);
  float (*hsh)[64]  = (float (*)[64])(exb);                //  4096 B  h0 stage
  float (*wacc)[64] = (float (*)[64])(exb + 4096);         // 15360 B  w accum
  u16   (*wbf)[80]  = (u16   (*)[80])(exb + 19456);        // 10240 B  w A-operand
  float (*klds)[10] = (float (*)[10])(exb + 29696);        //  2560 B  kappa
  float (*ash)[10]  = (float (*)[10])(exb + 32256);
  float (*bsh)[10]  = (float (*)[10])(exb + 34816);
  float (*ksh)[10]  = (float (*)[10])(exb + 37376);        // end 39936
  float (*wwin_l)[16] = (float (*)[16])(exb + 39936);      //  1920 B Wwin slice
  unsigned char* text_l = (unsigned char*)(exb + 41856);   //  4096 B text (u8)
  int*   tlen_l = (int*)(exb + 45952);                     //   256 B
  float* bwin_l = (float*)(exb + 46208);                   //   120 B, end 46328

  const u16 *Ap; u16 *yr;
  const float *bi, *bh, *cin; int ohh, occ;
  if (grp == 0){ Ap=p.A0; yr=p.y0; bi=p.bih0; bh=p.bhh0; cin=p.h0c; ohh=O_H0H; occ=O_H0C; }
  else if (grp == 1){ Ap=p.A1; yr=p.y1; bi=p.bih1; bh=p.bhh1; cin=p.h1c; ohh=O_H1H; occ=O_H1C; }
  else { Ap=p.A2; yr=p.y2; bi=p.bih2; bh=p.bhh2; cin=p.h2c; ohh=O_H2H; occ=O_H2C; }

  // ---- stage weight slice into LDS (once) ----
  {
    const u16* gsrc; int cnt;
    if (grp == 0){ gsrc = p.B0 + (size_t)s*26624; cnt = 26624; }
    else if (grp == 1){ gsrc = p.B1 + (size_t)s*55296; cnt = 55296; }
    else { gsrc = p.B2 + (size_t)s*55296; cnt = 55296; }
    for (int i = tid*8; i < cnt; i += NT*8)
      *reinterpret_cast<short8*>(&wB[i]) = *reinterpret_cast<const short8*>(gsrc + i);
    if (grp == 0){
      const u16* gw = p.Bw0 + (size_t)s*4096;
      for (int i = tid*8; i < 4096; i += NT*8)
        *reinterpret_cast<short8*>(wBw + i) = *reinterpret_cast<const short8*>(gw + i);
    }
  }

  for (int cell = tid; cell < 1024; cell += NT){
    int jj = cell >> 6, b = cell & 63;
    clds[jj][b] = cin[b*400 + s*16 + jj];
  }
  if (tid < 64){
    int jj = tid >> 2, gg = tid & 3;
    bsum[tid] = bi[gg*400 + s*16 + jj] + bh[gg*400 + s*16 + jj];
  }
  if (grp == 0){
    for (int cell = tid; cell < 640; cell += NT) klds[cell/10][cell%10] = p.pk[cell];
    for (int cell = tid; cell < 64*80; cell += NT){
      int b = cell/80, k = cell%80;
      wbf[b][k] = (k < 60) ? f2bf(p.pw[b*60 + k]) : (u16)0;
    }
    if (tid < 480) wwin_l[tid>>4][tid&15] = p.Wwin[(tid>>4)*400 + s*16 + (tid&15)];
    for (int cell = tid; cell < 4096; cell += NT)
      text_l[cell] = (unsigned char)p.text[cell];
    if (tid < 64) tlen_l[tid] = p.tlen[tid];
    if (tid < 30) bwin_l[tid] = p.bwin[tid];
  }
  __syncthreads();

  for (int r = 0; r < 515; ++r){
    const int t = r - lag;

    // ---- cross-group ordering via FLUSHED gens (pre-satisfied by lag) ----
    if (grp == 1 && r >= 2 && r <= 513) waitgen(p.bar + GBASE(0) + FGOFF, (unsigned)r);
    if (grp == 2 && r >= 3 && r <= 514) waitgen(p.bar + GBASE(1) + FGOFF, (unsigned)r);

    // ---- grp0: hoist obuf bank loads then A0 frags ----
    float ovs[4][5];
    if (grp == 0 && r >= 1 && r <= 512){
      const float* ob = p.obuf + (size_t)((r-1)%3)*9600;
      #pragma unroll
      for (int i = 0; i < 4; ++i){
        int cell = tid + i*NT;
        if (cell < 1920){
          #pragma unroll
          for (int bk = 0; bk < 5; ++bk)
            ovs[i][bk] = __hip_atomic_load(&ob[bk*1920 + cell], __ATOMIC_RELAXED, __HIP_MEMORY_SCOPE_AGENT);
        }
      }
    }
    short8 a0r[13];
    if (grp == 0 && t < 512){
      const u16* Ab = p.A0 + ((size_t)(t*4 + bq)*13)*512 + (size_t)lane*8;
      #pragma unroll
      for (int kb = 0; kb < 13; ++kb)
        a0r[kb] = *reinterpret_cast<const short8*>(Ab + (size_t)kb*512);
    }

    // ---- window finalize for t = r-1 (replicated across the 25 L0 WGs) ----
    if (grp == 0 && r >= 1 && r <= 512){
      const int tw = r - 1;
      #pragma unroll
      for (int i = 0; i < 4; ++i){
        int cell = tid + i*NT;
        if (cell < 1920){
          int b = cell & 63, n = cell >> 6;
          float o = ovs[i][0]+ovs[i][1]+ovs[i][2]+ovs[i][3]+ovs[i][4] + bwin_l[n];
          if (n < 10) ash[b][n] = __expf(o);
          else if (n < 20) bsh[b][n-10] = __expf(o);
          else { float kn = klds[b][n-20] + 0.05f*__expf(o); klds[b][n-20] = kn; ksh[b][n-20] = kn; }
        }
      }
      for (int cell = tid; cell < 3840; cell += NT) ((float*)wacc)[cell] = 0.f;
      __syncthreads();
      {
        // thread owns b = tid>>3, u = (tid&7)*8 .. +7 -> Gaussian params in regs
        // (240 per-thread LDS re-reads in R12 -> 30; atomicAdd aliasing blocked CSE)
        const int b = tid >> 3, u0 = (tid & 7) * 8;
        const int tl = tlen_l[b];
        float av[10], bv[10], kv[10];
        if (u0 < tl){
          #pragma unroll
          for (int n = 0; n < 10; ++n){ av[n]=ash[b][n]; bv[n]=bsh[b][n]; kv[n]=ksh[b][n]; }
        }
        #pragma unroll
        for (int j = 0; j < 8; ++j){
          int u = u0 + j;
          float phi = 0.f;
          if (u < tl){
            #pragma unroll
            for (int n = 0; n < 10; ++n){
              float d = kv[n] - (float)u;
              phi += av[n]*__expf(-bv[n]*d*d);
            }
            atomicAdd(&wacc[text_l[b*64 + u]][b], phi);
          }
          int cell = b*64 + u;
          if (((cell*25) >> 12) == s)   // O_AL spread over 25 WGs (no straggler)
            p.out[O_AL + ((size_t)tw*64 + b)*64 + u] = phi;
        }
      }
      __syncthreads();
      for (int cell = tid; cell < 3840; cell += NT){
        int b = cell & 63, l = cell >> 6;
        u16 wv = f2bf(wacc[l][b]);
        wbf[b][l] = wv;
        if (s == 1) p.A1[aidx(tw,b,400+l,27)] = wv;
        if (s == 2) p.A2[aidx(tw,b,400+l,27)] = wv;
        if (s == 0 && tw == 511) p.out[O_PW + b*60 + l] = wacc[l][b];
      }
      if (s == 0 && tw == 511)
        for (int cell = tid; cell < 640; cell += NT) p.out[O_PK + cell] = klds[cell/10][cell%10];
      __syncthreads();
    }

    // ---- gate GEMM + LSTM pointwise ----
    if (t >= 0 && t < 512){
      float4v acc[2] = {{0.f,0.f,0.f,0.f},{0.f,0.f,0.f,0.f}};
      if (grp == 0){
        #pragma unroll
        for (int kb = 0; kb < 13; ++kb){
          #pragma unroll
          for (int u2 = 0; u2 < 2; ++u2){
            int tt = th*2 + u2;
            short8 bf = *reinterpret_cast<const short8*>(wB + (size_t)(tt*13 + kb)*512 + (size_t)lane*8);
            acc[u2] = __builtin_amdgcn_mfma_f32_16x16x32_bf16(a0r[kb], bf, acc[u2], 0, 0, 0);
          }
        }
        const int m = lane & 15, q = (lane >> 4) & 3;
        #pragma unroll
        for (int kb = 0; kb < 2; ++kb){
          short8 af = *reinterpret_cast<const short8*>(&wbf[bq*16 + m][kb*32 + q*8]);
          #pragma unroll
          for (int u2 = 0; u2 < 2; ++u2){
            int tt = th*2 + u2;
            short8 bf = *reinterpret_cast<const short8*>(wBw + (size_t)((tt*2 + kb))*512 + (size_t)lane*8);
            acc[u2] = __builtin_amdgcn_mfma_f32_16x16x32_bf16(af, bf, acc[u2], 0, 0, 0);
          }
        }
      } else {
        short8 a1r[27];
        const u16* Ab = Ap + ((size_t)(t*4 + bq)*27)*512 + (size_t)lane*8;
        #pragma unroll
        for (int kb = 0; kb < 27; ++kb)
          a1r[kb] = *reinterpret_cast<const short8*>(Ab + (size_t)kb*512);
        #pragma unroll
        for (int kb = 0; kb < 27; ++kb){
          #pragma unroll
          for (int u2 = 0; u2 < 2; ++u2){
            int tt = th*2 + u2;
            short8 bf = *reinterpret_cast<const short8*>(wB + (size_t)(tt*27 + kb)*512 + (size_t)lane*8);
            acc[u2] = __builtin_amdgcn_mfma_f32_16x16x32_bf16(a1r[kb], bf, acc[u2], 0, 0, 0);
          }
        }
      }
      {
        const int c = lane & 15, rb = bq*16 + ((lane>>4)<<2);
        #pragma unroll
        for (int u2 = 0; u2 < 2; ++u2){
          int tt = th*2 + u2;
          #pragma unroll
          for (int rr2 = 0; rr2 < 4; ++rr2)
            ldsg[rb+rr2][tt*16 + c] = acc[u2][rr2];
        }
      }
      __syncthreads();
      for (int cell = tid; cell < 1024; cell += NT){
        int jj = cell >> 6, b = cell & 63;
        int j = s*16 + jj, tt = jj >> 2, jo = jj & 3;
        float gi = ldsg[b][tt*16 +      jo] + bsum[jj*4 + 0];
        float gf = ldsg[b][tt*16 +  4 + jo] + bsum[jj*4 + 1];
        float gg = ldsg[b][tt*16 +  8 + jo] + bsum[jj*4 + 2];
        float go = ldsg[b][tt*16 + 12 + jo] + bsum[jj*4 + 3];
        float cp = clds[jj][b];
        float cn = sigm(gf)*cp + sigm(gi)*tanh_f(gg);
        float hh = sigm(go)*tanh_f(cn);
        clds[jj][b] = cn;
        u16 hb = f2bf(hh);
        yr[((size_t)t*64 + b)*400 + j] = hb;
        if (grp == 0){
          p.A1[aidx(t,b,j,27)] = hb;
          if (t < 511) p.A0[aidx(t+1,b,3+j,13)] = hb;
          hsh[jj][b] = hh;
        } else if (grp == 1){
          p.A2[aidx(t,b,j,27)] = hb;
          if (t < 511) p.A1[aidx(t+1,b,463+j,27)] = hb;
        } else {
          if (t < 511) p.A2[aidx(t+1,b,463+j,27)] = hb;
        }
        if (t == 511){ p.out[ohh + b*400 + j] = hh; p.out[occ + b*400 + j] = cn; }
      }
      if (grp == 0){
        __syncthreads();
        float* od = p.obuf + (size_t)(r%3)*9600 + (size_t)(s%5)*1920;
        for (int cell = tid; cell < 1920; cell += NT){
          int b = cell & 63, n = cell >> 6;
          float sum = 0.f;
          #pragma unroll
          for (int jj = 0; jj < 16; ++jj)
            sum += hsh[jj][b] * wwin_l[n][jj];
          atomicAdd(&od[n*64 + b], sum);
        }
      }
    }
    // grp0 zeroes its next-next o-slot (consumed at round r-1 -> safe), spread over 25 WGs
    if (grp == 0 && r <= 510 && tid < 384){
      float* oz = p.obuf + (size_t)((r+1)%3)*9600 + (size_t)s*384;
      __hip_atomic_store(&oz[tid], 0.f, __ATOMIC_RELAXED, __HIP_MEMORY_SCOPE_AGENT);
    }
    if (r < 514) gsyncx(fl, s, (unsigned)(r+1));
  }
}

// ---------------- output heads ----------------
__global__ __launch_bounds__(256) void kproj(P p){
  const int t = blockIdx.x >> 3, ns = blockIdx.x & 7;
  const int tid = threadIdx.x, lane = tid & 63, wave = tid >> 6;
  const int m = lane & 15, q = lane >> 4;
  float4v acc = {0.f,0.f,0.f,0.f};
  const size_t rowA = (size_t)t*64 + wave*16 + m;
  const u16* Bb = p.BP + ((size_t)ns*38)*512 + (size_t)lane*8;
  for (int kb = 0; kb < 38; ++kb){
    int k0 = kb*32 + q*8;
    const u16* src; int off;
    if (k0 < 400){ src = p.y0; off = k0; }
    else if (k0 < 800){ src = p.y1; off = k0 - 400; }
    else if (k0 < 1200){ src = p.y2; off = k0 - 800; }
    else { src = p.y0; off = 0; }     // B rows are zero for k>=1200
    short8 af = *reinterpret_cast<const short8*>(src + rowA*400 + off);
    short8 bf = *reinterpret_cast<const short8*>(Bb + (size_t)kb*512);
    acc = __builtin_amdgcn_mfma_f32_16x16x32_bf16(af, bf, acc, 0, 0, 0);
  }
  const int j = ns*16 + (lane & 15);
  const int bo = wave*16 + q*4;
  #pragma unroll
  for (int rr = 0; rr < 4; ++rr){
    float v = acc[rr];
    size_t ro = (size_t)t*64 + bo + rr;
    if (j < 40)        p.out[O_MEANS + ro*40 + j]        = v + p.bmu[j];
    else if (j < 80)   p.out[O_LS    + ro*40 + (j-40)]   = v + p.bls[j-40];
    else if (j < 100)  p.out[O_RHO   + ro*20 + (j-80)]   = tanhf(v + p.brho[j-80]);
    else if (j < 120)  p.out[O_PI    + ro*20 + (j-100)]  = v + p.bpi[j-100];
    else if (j == 120) p.out[O_EOS   + ro]               = v + p.beos[0];
  }
}

// ---------------- host ----------------
extern "C" void kernel_launch(void* const* d_in, const int* in_sizes, int n_in,
                              void* d_out, int out_size, void* d_ws, size_t ws_size,
                              hipStream_t stream){
  P p;
  p.strokes = (const float*)d_in[0];
  p.text    = (const int*)  d_in[1];
  p.tlen    = (const int*)  d_in[2];
  p.h0h = (const float*)d_in[3];  p.h0c = (const float*)d_in[4];
  p.h1h = (const float*)d_in[5];  p.h1c = (const float*)d_in[6];
  p.h2h = (const float*)d_in[7];  p.h2c = (const float*)d_in[8];
  p.pw  = (const float*)d_in[9];  p.pk  = (const float*)d_in[10];
  const float* Wih0 = (const float*)d_in[11]; const float* Whh0 = (const float*)d_in[12];
  p.bih0 = (const float*)d_in[13]; p.bhh0 = (const float*)d_in[14];
  const float* Wih1 = (const float*)d_in[15]; const float* Whh1 = (const float*)d_in[16];
  p.bih1 = (const float*)d_in[17]; p.bhh1 = (const float*)d_in[18];
  const float* Wih2 = (const float*)d_in[19]; const float* Whh2 = (const float*)d_in[20];
  p.bih2 = (const float*)d_in[21]; p.bhh2 = (const float*)d_in[22];
  p.Wwin = (const float*)d_in[23]; p.bwin = (const float*)d_in[24];
  const float* Wmu  = (const float*)d_in[25]; p.bmu  = (const float*)d_in[26];
  const float* Wls  = (const float*)d_in[27]; p.bls  = (const float*)d_in[28];
  const float* Wrho = (const float*)d_in[29]; p.brho = (const float*)d_in[30];
  const float* Wpi  = (const float*)d_in[31]; p.bpi  = (const float*)d_in[32];
  const float* Weos = (const float*)d_in[33]; p.beos = (const float*)d_in[34];
  p.out = (float*)d_out;

  char* w = (char*)d_ws; size_t off = 0;
  auto alloc = [&](size_t bytes)->void*{ void* r = w + off; off += (bytes + 511) & ~(size_t)511; return r; };
  p.B0  = (u16*)alloc((size_t)25*4*13*512*2);
  p.B1  = (u16*)alloc((size_t)25*4*27*512*2);
  p.B2  = (u16*)alloc((size_t)25*4*27*512*2);
  p.Bw0 = (u16*)alloc((size_t)25*4*2*512*2);
  p.BP  = (u16*)alloc((size_t)8*38*512*2);
  p.A0  = (u16*)alloc((size_t)512*4*13*512*2);
  p.A1  = (u16*)alloc((size_t)512*4*27*512*2);
  p.A2  = (u16*)alloc((size_t)512*4*27*512*2);
  p.y0  = (u16*)alloc((size_t)512*64*400*2);
  p.y1  = (u16*)alloc((size_t)512*64*400*2);
  p.y2  = (u16*)alloc((size_t)512*64*400*2);
  p.obuf= (float*)alloc((size_t)3*9600*4);
  p.bar = (unsigned*)alloc((size_t)4096*4);

  kpackB<<<dim3(2600), dim3(256), 0, stream>>>(Wih0, Whh0, p.B0, 13, 3,   63,  25*4*13*512);
  kpackB<<<dim3(5400), dim3(256), 0, stream>>>(Wih1, Whh1, p.B1, 27, 463, 463, 25*4*27*512);
  kpackB<<<dim3(5400), dim3(256), 0, stream>>>(Wih2, Whh2, p.B2, 27, 463, 463, 25*4*27*512);
  kpackBw<<<dim3(400), dim3(256), 0, stream>>>(Wih0, p.Bw0);
  kpackBP<<<dim3(608), dim3(256), 0, stream>>>(Wmu, Wls, Wrho, Wpi, Weos, p.BP);
  kfillA<<<dim3(4096), dim3(256), 0, stream>>>(p);
  kinit<<<dim3(429), dim3(256), 0, stream>>>(p);

  // 256 WGs at 1 WG/CU (LDS-bound) => exactly 32 per XCD; roles via XCC_ID.
  // 512 threads/WG = 8 waves = 2 waves/SIMD (proven no-spill config).
  kmain<<<dim3(256), dim3(NT), 0, stream>>>(p);

  kproj<<<dim3(4096), dim3(256), 0, stream>>>(p);
}